// Round 10
// baseline (150.814 us; speedup 1.0000x reference)
//
#include <hip/hip_runtime.h>

#define B_TOTAL 131072
#define DIM 256
#define NCAT 10
#define NPART 16

#define K1_BLOCKS 1024
#define K1_WAVES  (K1_BLOCKS * 4)
#define K3_BLOCKS 1024
#define SPP (K1_BLOCKS / NPART)          // 64 slabs per partial

// ws layout (floats)
#define SCR_STRIDE 2576                  // 2560 sums + 16 counts per block
#define WS_SCRATCH 0
#define WS_PART    (K1_BLOCKS * SCR_STRIDE)            // [160][272]
#define WS_PUSED   (WS_PART + NCAT * NPART * 272)      // [10][256]
#define WS_LOSSP   (WS_PUSED + NCAT * DIM)             // [K3_BLOCKS]
#define WS_CTR     (WS_LOSSP + K3_BLOCKS)              // 2 u32 counters

typedef __attribute__((ext_vector_type(8))) short bf16x8;
typedef __attribute__((ext_vector_type(4))) float f32x4;

union Frag { bf16x8 v; unsigned u[4]; };

__device__ __forceinline__ float waveRedSum(float v) {
#pragma unroll
  for (int m = 1; m < 64; m <<= 1) v += __shfl_xor(v, m, 64);
  return v;
}

// pack two fp32 -> packed bf16 pair (RNE, finite inputs)
__device__ __forceinline__ unsigned pk2(float a, float b) {
  unsigned ua = __float_as_uint(a), ub = __float_as_uint(b);
  ua = (ua + 0x7fffu + ((ua >> 16) & 1u)) >> 16;
  ub = (ub + 0x7fffu + ((ub >> 16) & 1u)) >> 16;
  return ua | (ub << 16);
}

// ---------------- K1: row-normalize + per-block segment sums ----------------
__global__ __launch_bounds__(256) void k1_segsum(
    const float* __restrict__ feats, const int* __restrict__ cats,
    float* __restrict__ scratch, unsigned* __restrict__ ctrs) {
  __shared__ float acc[4][NCAT * DIM];   // 40 KB -> 4 blocks/CU, 16 waves/CU
  __shared__ float accCnt[4][16];

  const int tid = threadIdx.x;
  const int w = tid >> 6;
  const int lane = tid & 63;

  if (blockIdx.x == 0 && tid < 2) ctrs[tid] = 0u;   // reset merge counters

  for (int i = tid; i < 4 * NCAT * DIM; i += 256) (&acc[0][0])[i] = 0.0f;
  __syncthreads();

  float* accW = acc[w];
  int cnt = 0;                       // lane c (<10) counts rows with cat==c
  int qd = blockIdx.x * 4 + w;       // quad index: rows 4qd..4qd+3

  const float* fp = feats + (size_t)qd * 4 * DIM + lane * 4;
  float4 A0 = *(const float4*)(fp);
  float4 A1 = *(const float4*)(fp + DIM);
  float4 A2 = *(const float4*)(fp + 2 * DIM);
  float4 A3 = *(const float4*)(fp + 3 * DIM);
  int c0 = cats[4 * qd], c1 = cats[4 * qd + 1];
  int c2 = cats[4 * qd + 2], c3 = cats[4 * qd + 3];

  for (int it = 0; it < 8; ++it) {
    const int qn = qd + K1_WAVES;
    float4 B0, B1, B2, B3;
    int d0 = 0, d1 = 0, d2 = 0, d3 = 0;
    if (it < 7) {                    // prefetch next quad
      const float* fn = feats + (size_t)qn * 4 * DIM + lane * 4;
      B0 = *(const float4*)(fn);
      B1 = *(const float4*)(fn + DIM);
      B2 = *(const float4*)(fn + 2 * DIM);
      B3 = *(const float4*)(fn + 3 * DIM);
      d0 = cats[4 * qn]; d1 = cats[4 * qn + 1];
      d2 = cats[4 * qn + 2]; d3 = cats[4 * qn + 3];
    }

    float s0 = A0.x * A0.x + A0.y * A0.y + A0.z * A0.z + A0.w * A0.w;
    float s1 = A1.x * A1.x + A1.y * A1.y + A1.z * A1.z + A1.w * A1.w;
    float s2 = A2.x * A2.x + A2.y * A2.y + A2.z * A2.z + A2.w * A2.w;
    float s3 = A3.x * A3.x + A3.y * A3.y + A3.z * A3.z + A3.w * A3.w;
#pragma unroll
    for (int m = 1; m < 64; m <<= 1) {
      s0 += __shfl_xor(s0, m, 64);
      s1 += __shfl_xor(s1, m, 64);
      s2 += __shfl_xor(s2, m, 64);
      s3 += __shfl_xor(s3, m, 64);
    }
    const float i0 = __builtin_amdgcn_rsqf(fmaxf(s0, 1e-24f));
    const float i1 = __builtin_amdgcn_rsqf(fmaxf(s1, 1e-24f));
    const float i2 = __builtin_amdgcn_rsqf(fmaxf(s2, 1e-24f));
    const float i3 = __builtin_amdgcn_rsqf(fmaxf(s3, 1e-24f));

    float4* p;
    float4 t;
    p = (float4*)&accW[c0 * DIM + lane * 4]; t = *p;
    t.x += A0.x * i0; t.y += A0.y * i0; t.z += A0.z * i0; t.w += A0.w * i0; *p = t;
    p = (float4*)&accW[c1 * DIM + lane * 4]; t = *p;
    t.x += A1.x * i1; t.y += A1.y * i1; t.z += A1.z * i1; t.w += A1.w * i1; *p = t;
    p = (float4*)&accW[c2 * DIM + lane * 4]; t = *p;
    t.x += A2.x * i2; t.y += A2.y * i2; t.z += A2.z * i2; t.w += A2.w * i2; *p = t;
    p = (float4*)&accW[c3 * DIM + lane * 4]; t = *p;
    t.x += A3.x * i3; t.y += A3.y * i3; t.z += A3.z * i3; t.w += A3.w * i3; *p = t;

    cnt += (lane == c0) + (lane == c1) + (lane == c2) + (lane == c3);

    if (it < 7) {
      A0 = B0; A1 = B1; A2 = B2; A3 = B3;
      c0 = d0; c1 = d1; c2 = d2; c3 = d3;
      qd = qn;
    }
  }

  if (lane < 16) accCnt[w][lane] = (float)cnt;
  __syncthreads();

  float* dst = scratch + (size_t)blockIdx.x * SCR_STRIDE;
  for (int i = tid; i < NCAT * DIM; i += 256)
    dst[i] = acc[0][i] + acc[1][i] + acc[2][i] + acc[3][i];
  if (tid < 16)
    dst[2560 + tid] = accCnt[0][tid] + accCnt[1][tid]
                    + accCnt[2][tid] + accCnt[3][tid];
}

// ---------------- K2 fused: slab reduce; last block does EMA ----------------
__global__ __launch_bounds__(256) void k2_fused(
    const float* __restrict__ protos, const float* __restrict__ scratch,
    float* __restrict__ part, float* __restrict__ pused,
    unsigned* __restrict__ ctr) {
  __shared__ float red[4];
  __shared__ int lastFlag;
  const int b = blockIdx.x;          // 0..159
  const int c = b >> 4, p = b & 15;
  const int d = threadIdx.x;
  const int w = d >> 6, lane = d & 63;

  const float* base = scratch + (size_t)p * SPP * SCR_STRIDE + c * DIM + d;
  float s0 = 0.f, s1 = 0.f, s2 = 0.f, s3 = 0.f;
#pragma unroll 4
  for (int s = 0; s < SPP; s += 4) {
    s0 += base[(size_t)s * SCR_STRIDE];
    s1 += base[(size_t)(s + 1) * SCR_STRIDE];
    s2 += base[(size_t)(s + 2) * SCR_STRIDE];
    s3 += base[(size_t)(s + 3) * SCR_STRIDE];
  }
  part[b * 272 + d] = (s0 + s1) + (s2 + s3);

  if (d < 64) {   // 64 lanes <-> 64 slabs: count partial
    float cn = scratch[((size_t)p * SPP + d) * SCR_STRIDE + 2560 + c];
    cn = waveRedSum(cn);
    if (d == 0) part[b * 272 + 256] = cn;
  }

  __threadfence();                   // release this block's part writes
  __syncthreads();
  if (d == 0) lastFlag = (atomicAdd(ctr, 1u) == NCAT * NPART - 1);
  __syncthreads();
  if (!lastFlag) return;
  __threadfence();                   // acquire all blocks' part writes

  // final reduce + EMA for all 10 categories (one block)
  for (int c2 = 0; c2 < NCAT; ++c2) {
    float s = 0.f, cnt = 0.f;
#pragma unroll
    for (int p2 = 0; p2 < NPART; p2++) {
      s += part[(c2 * NPART + p2) * 272 + d];
      cnt += part[(c2 * NPART + p2) * 272 + 256];
    }
    const float pv = protos[c2 * DIM + d];
    const float v = 0.9f * pv + 0.1f * (s / fmaxf(cnt, 1.0f));
    const float vv = waveRedSum(v * v);
    if (lane == 0) red[w] = vv;
    __syncthreads();
    const float n = fmaxf(sqrtf(red[0] + red[1] + red[2] + red[3]), 1e-12f);
    pused[c2 * DIM + d] = (cnt > 0.0f) ? v / n : pv;
    __syncthreads();
  }
}

// ---------------- K3 fused: MFMA sims + loss + aligned out; last block
// finalizes the loss -------------------------------------------------------
__global__ __launch_bounds__(256) void k3_fused(
    const float* __restrict__ feats, const int* __restrict__ cats,
    const float* __restrict__ pused, float* __restrict__ out,
    float* __restrict__ partials, unsigned* __restrict__ ctr) {
  __shared__ unsigned short ot[4][16 * 272];   // 34.8 KB
  __shared__ float wloss[4];
  __shared__ int lastFlag;

  const int tid = threadIdx.x;
  const int w = tid >> 6;
  const int l = tid & 63;
  const int q = l >> 4;
  const int mr = l & 15;
  char* otb = (char*)&ot[w][0];

  // B fragments (prototypes as bf16)
  Frag bfr[8];
  {
    const float* prow = pused + mr * DIM;
#pragma unroll
    for (int s = 0; s < 8; s++) {
      float4 b0 = make_float4(0.f, 0.f, 0.f, 0.f), b1 = b0;
      const int kb = q * 8 + 32 * s;
      if (mr < NCAT) {
        b0 = *(const float4*)(prow + kb);
        b1 = *(const float4*)(prow + kb + 4);
      }
      bfr[s].u[0] = pk2(b0.x, b0.y); bfr[s].u[1] = pk2(b0.z, b0.w);
      bfr[s].u[2] = pk2(b1.x, b1.y); bfr[s].u[3] = pk2(b1.z, b1.w);
    }
  }

  constexpr float KZ = (1.0f / 0.07f) * 1.44269504088896f;
  constexpr float LN2 = 0.69314718056f;
  float lossAcc = 0.0f;

  const int waveG = blockIdx.x * 4 + w;
  const int nwaves = K3_BLOCKS * 4;

  for (int t = waveG; t < B_TOTAL / 16; t += nwaves) {
    const int r0 = t * 16;

    // ---- load F tile, sumsq, bf16 A-frags ----
    const float* frow = feats + (size_t)(r0 + mr) * DIM;
    Frag afr[8];
    float ss = 0.0f;
#pragma unroll
    for (int s = 0; s < 8; s++) {
      const int kb = q * 8 + 32 * s;
      const float4 u0 = *(const float4*)(frow + kb);
      const float4 u1 = *(const float4*)(frow + kb + 4);
      ss += u0.x * u0.x + u0.y * u0.y + u0.z * u0.z + u0.w * u0.w
          + u1.x * u1.x + u1.y * u1.y + u1.z * u1.z + u1.w * u1.w;
      afr[s].u[0] = pk2(u0.x, u0.y); afr[s].u[1] = pk2(u0.z, u0.w);
      afr[s].u[2] = pk2(u1.x, u1.y); afr[s].u[3] = pk2(u1.z, u1.w);
    }
    ss += __shfl_xor(ss, 16, 64);
    ss += __shfl_xor(ss, 32, 64);
    const float inv = __builtin_amdgcn_rsqf(fmaxf(ss, 1e-24f));

    // ---- sims via MFMA ----
    f32x4 acc = {0.f, 0.f, 0.f, 0.f};
#pragma unroll
    for (int s = 0; s < 8; s++)
      acc = __builtin_amdgcn_mfma_f32_16x16x32_bf16(afr[s].v, bfr[s].v, acc, 0, 0, 0);

    // ---- per-reg softmax (row r0+4q+j; lane's category = mr) ----
    float stv[4];
#pragma unroll
    for (int j = 0; j < 4; j++) {
      const float invj = __shfl(inv, 4 * q + j, 64);
      const int catj = cats[r0 + 4 * q + j];
      const float z = acc[j] * (invj * KZ);
      float zm = (mr < NCAT) ? z : -3.0e38f;
#pragma unroll
      for (int m = 1; m < 16; m <<= 1) zm = fmaxf(zm, __shfl_xor(zm, m, 64));
      float e = (mr < NCAT) ? __builtin_amdgcn_exp2f(z - zm) : 0.0f;
      float sv = (mr == catj) ? z : 0.0f;
#pragma unroll
      for (int m = 1; m < 16; m <<= 1) {
        e += __shfl_xor(e, m, 64);
        sv += __shfl_xor(sv, m, 64);
      }
      lossAcc += LN2 * (zm + __builtin_amdgcn_logf(e) - sv);
      stv[j] = sv;
    }

    // ---- aligned vector for row (r0+mr) into swizzled LDS ----
    const int srcg = (mr >> 2) * 16;
    const float s0 = __shfl(stv[0], srcg, 64);
    const float s1 = __shfl(stv[1], srcg, 64);
    const float s2 = __shfl(stv[2], srcg, 64);
    const float s3 = __shfl(stv[3], srcg, 64);
    const int jj = mr & 3;
    const float stm = (jj == 0) ? s0 : ((jj == 1) ? s1 : ((jj == 2) ? s2 : s3));
    const float simn = stm * (0.07f * LN2);
    const float inv2 = __builtin_amdgcn_rsqf(fmaxf(0.58f + 0.42f * simn, 1e-24f));
    const int catm = cats[r0 + mr];
    const float c0f = 0.7f * inv;
    const int psrc = q * 16 + catm;
    const int wrb = mr * 544;
    const int wsz = (mr & 7) << 4;

#pragma unroll
    for (int s = 0; s < 8; s++) {
      const int kb = q * 8 + 32 * s;
      unsigned pw0 = __shfl((int)bfr[s].u[0], psrc, 64);
      unsigned pw1 = __shfl((int)bfr[s].u[1], psrc, 64);
      unsigned pw2 = __shfl((int)bfr[s].u[2], psrc, 64);
      unsigned pw3 = __shfl((int)bfr[s].u[3], psrc, 64);
      const unsigned pws[4] = {pw0, pw1, pw2, pw3};
      float av[8];
#pragma unroll
      for (int h = 0; h < 4; h++) {
        const unsigned fp = afr[s].u[h];
        const unsigned pp = pws[h];
        const float f0 = __uint_as_float(fp << 16);
        const float f1 = __uint_as_float(fp & 0xffff0000u);
        const float p0 = __uint_as_float(pp << 16);
        const float p1 = __uint_as_float(pp & 0xffff0000u);
        av[2 * h]     = (c0f * f0 + 0.3f * p0) * inv2;
        av[2 * h + 1] = (c0f * f1 + 0.3f * p1) * inv2;
      }
      uint4 pk;
      pk.x = pk2(av[0], av[1]); pk.y = pk2(av[2], av[3]);
      pk.z = pk2(av[4], av[5]); pk.w = pk2(av[6], av[7]);
      *(uint4*)(otb + ((wrb + 2 * kb) ^ wsz)) = pk;
    }

    // ---- readback (2x aligned b64 per row-step) + nt dwordx4 stores ----
    float* outr = out + (size_t)r0 * DIM;   // region element e -> outr[1+e]
#pragma unroll
    for (int i = 0; i < 16; ++i) {
      if (i == 15 && l == 63) continue;     // last element handled by edge lane
      const int kidx = i * 64 + l + 1;
      const int rb = 544 * i;
      const int sz = (i & 7) << 4;
      // b64 A: cols 4l..4l+3 ; b64 B: cols 4l+4..4l+7 (or next-row 0..3 for l==63)
      const int aA = (rb + 8 * l) ^ sz;
      const int aB = (l == 63) ? ((rb + 544) ^ (((i + 1) & 7) << 4))
                               : ((rb + 8 * l + 8) ^ sz);
      const unsigned long long A = *(const unsigned long long*)(otb + aA);
      const unsigned long long Bv = *(const unsigned long long*)(otb + aB);
      const unsigned a1 = (unsigned)(A >> 32);
      const unsigned b0 = (unsigned)Bv;
      const unsigned b1 = (unsigned)(Bv >> 32);
      f32x4 sv;
      sv.x = __uint_as_float(a1 & 0xffff0000u);   // col 4l+3
      sv.y = __uint_as_float(b0 << 16);           // col 4l+4 (or next-row 0)
      sv.z = __uint_as_float(b0 & 0xffff0000u);   // col 4l+5 (or next-row 1)
      sv.w = __uint_as_float(b1 << 16);           // col 4l+6 (or next-row 2)
      __builtin_nontemporal_store(sv, (f32x4*)(outr + 4 * kidx));
    }
    // edge elements: region e = 0,1,2 and e = 4095
    if (l < 3) {
      const float ev = __uint_as_float(
          (unsigned)(*(const unsigned short*)(otb + 2 * l)) << 16);
      __builtin_nontemporal_store(ev, outr + 1 + l);
    }
    if (l == 3) {
      const float ev = __uint_as_float(
          (unsigned)(*(const unsigned short*)(otb + ((544 * 15 + 510) ^ 112))) << 16);
      __builtin_nontemporal_store(ev, outr + 4096);
    }
  }

  const float s = waveRedSum(lossAcc);
  if (l == 0) wloss[w] = s * 0.0625f;   // each row counted by 16 lanes
  __syncthreads();
  if (tid == 0) {
    partials[blockIdx.x] = wloss[0] + wloss[1] + wloss[2] + wloss[3];
    __threadfence();
    lastFlag = (atomicAdd(ctr, 1u) == K3_BLOCKS - 1);
  }
  __syncthreads();
  if (!lastFlag) return;
  __threadfence();                        // acquire all partials

  float fs = 0.f;
  for (int i = tid; i < K3_BLOCKS; i += 256) fs += partials[i];
  fs = waveRedSum(fs);
  if (l == 0) wloss[w] = fs;
  __syncthreads();
  if (tid == 0)
    out[0] = (wloss[0] + wloss[1] + wloss[2] + wloss[3]) * (1.0f / (float)B_TOTAL);
}

// ============================================================================
extern "C" void kernel_launch(void* const* d_in, const int* in_sizes, int n_in,
                              void* d_out, int out_size, void* d_ws, size_t ws_size,
                              hipStream_t stream) {
  const float* feats = (const float*)d_in[0];
  const int* cats = (const int*)d_in[1];
  const float* protos = (const float*)d_in[2];
  float* out = (float*)d_out;
  float* ws = (float*)d_ws;
  unsigned* ctrs = (unsigned*)(ws + WS_CTR);

  k1_segsum<<<K1_BLOCKS, 256, 0, stream>>>(feats, cats, ws + WS_SCRATCH, ctrs);
  k2_fused<<<NCAT * NPART, 256, 0, stream>>>(protos, ws + WS_SCRATCH,
                                             ws + WS_PART, ws + WS_PUSED,
                                             ctrs + 0);
  k3_fused<<<K3_BLOCKS, 256, 0, stream>>>(feats, cats, ws + WS_PUSED, out,
                                          ws + WS_LOSSP, ctrs + 1);
}

// Round 11
// 108.614 us; speedup vs baseline: 1.3885x; 1.3885x over previous
//
#include <hip/hip_runtime.h>

#define B_TOTAL 131072
#define DIM 256
#define NCAT 10
#define NPART 16

#define K1_BLOCKS 1024
#define K1_WAVES  (K1_BLOCKS * 4)
#define K3_BLOCKS 1024
#define SPP (K1_BLOCKS / NPART)          // 64 slabs per partial

// ws layout (floats)
#define SCR_STRIDE 2576                  // 2560 sums + 16 counts per block
#define WS_SCRATCH 0
#define WS_PART    (K1_BLOCKS * SCR_STRIDE)            // [160][272]
#define WS_PUSED   (WS_PART + NCAT * NPART * 272)      // [10][256]
#define WS_LOSSP   (WS_PUSED + NCAT * DIM)             // [K3_BLOCKS]
#define WS_CTR     (WS_LOSSP + K3_BLOCKS)              // 1 u32 counter

typedef __attribute__((ext_vector_type(8))) short bf16x8;
typedef __attribute__((ext_vector_type(4))) float f32x4;

union Frag { bf16x8 v; unsigned u[4]; };

__device__ __forceinline__ float waveRedSum(float v) {
#pragma unroll
  for (int m = 1; m < 64; m <<= 1) v += __shfl_xor(v, m, 64);
  return v;
}

// pack two fp32 -> packed bf16 pair (RNE, finite inputs)
__device__ __forceinline__ unsigned pk2(float a, float b) {
  unsigned ua = __float_as_uint(a), ub = __float_as_uint(b);
  ua = (ua + 0x7fffu + ((ua >> 16) & 1u)) >> 16;
  ub = (ub + 0x7fffu + ((ub >> 16) & 1u)) >> 16;
  return ua | (ub << 16);
}

// ---------------- K1: row-normalize + per-block segment sums ----------------
__global__ __launch_bounds__(256) void k1_segsum(
    const float* __restrict__ feats, const int* __restrict__ cats,
    float* __restrict__ scratch, unsigned* __restrict__ ctrs) {
  __shared__ float acc[4][NCAT * DIM];   // 40 KB -> 4 blocks/CU, 16 waves/CU
  __shared__ float accCnt[4][16];

  const int tid = threadIdx.x;
  const int w = tid >> 6;
  const int lane = tid & 63;

  if (blockIdx.x == 0 && tid == 0) ctrs[0] = 0u;   // reset k2 merge counter

  for (int i = tid; i < 4 * NCAT * DIM; i += 256) (&acc[0][0])[i] = 0.0f;
  __syncthreads();

  float* accW = acc[w];
  int cnt = 0;                       // lane c (<10) counts rows with cat==c
  int qd = blockIdx.x * 4 + w;       // quad index: rows 4qd..4qd+3

  const float* fp = feats + (size_t)qd * 4 * DIM + lane * 4;
  float4 A0 = *(const float4*)(fp);
  float4 A1 = *(const float4*)(fp + DIM);
  float4 A2 = *(const float4*)(fp + 2 * DIM);
  float4 A3 = *(const float4*)(fp + 3 * DIM);
  int c0 = cats[4 * qd], c1 = cats[4 * qd + 1];
  int c2 = cats[4 * qd + 2], c3 = cats[4 * qd + 3];

  for (int it = 0; it < 8; ++it) {
    const int qn = qd + K1_WAVES;
    float4 B0, B1, B2, B3;
    int d0 = 0, d1 = 0, d2 = 0, d3 = 0;
    if (it < 7) {                    // prefetch next quad
      const float* fn = feats + (size_t)qn * 4 * DIM + lane * 4;
      B0 = *(const float4*)(fn);
      B1 = *(const float4*)(fn + DIM);
      B2 = *(const float4*)(fn + 2 * DIM);
      B3 = *(const float4*)(fn + 3 * DIM);
      d0 = cats[4 * qn]; d1 = cats[4 * qn + 1];
      d2 = cats[4 * qn + 2]; d3 = cats[4 * qn + 3];
    }

    float s0 = A0.x * A0.x + A0.y * A0.y + A0.z * A0.z + A0.w * A0.w;
    float s1 = A1.x * A1.x + A1.y * A1.y + A1.z * A1.z + A1.w * A1.w;
    float s2 = A2.x * A2.x + A2.y * A2.y + A2.z * A2.z + A2.w * A2.w;
    float s3 = A3.x * A3.x + A3.y * A3.y + A3.z * A3.z + A3.w * A3.w;
#pragma unroll
    for (int m = 1; m < 64; m <<= 1) {
      s0 += __shfl_xor(s0, m, 64);
      s1 += __shfl_xor(s1, m, 64);
      s2 += __shfl_xor(s2, m, 64);
      s3 += __shfl_xor(s3, m, 64);
    }
    const float i0 = __builtin_amdgcn_rsqf(fmaxf(s0, 1e-24f));
    const float i1 = __builtin_amdgcn_rsqf(fmaxf(s1, 1e-24f));
    const float i2 = __builtin_amdgcn_rsqf(fmaxf(s2, 1e-24f));
    const float i3 = __builtin_amdgcn_rsqf(fmaxf(s3, 1e-24f));

    float4* p;
    float4 t;
    p = (float4*)&accW[c0 * DIM + lane * 4]; t = *p;
    t.x += A0.x * i0; t.y += A0.y * i0; t.z += A0.z * i0; t.w += A0.w * i0; *p = t;
    p = (float4*)&accW[c1 * DIM + lane * 4]; t = *p;
    t.x += A1.x * i1; t.y += A1.y * i1; t.z += A1.z * i1; t.w += A1.w * i1; *p = t;
    p = (float4*)&accW[c2 * DIM + lane * 4]; t = *p;
    t.x += A2.x * i2; t.y += A2.y * i2; t.z += A2.z * i2; t.w += A2.w * i2; *p = t;
    p = (float4*)&accW[c3 * DIM + lane * 4]; t = *p;
    t.x += A3.x * i3; t.y += A3.y * i3; t.z += A3.z * i3; t.w += A3.w * i3; *p = t;

    cnt += (lane == c0) + (lane == c1) + (lane == c2) + (lane == c3);

    if (it < 7) {
      A0 = B0; A1 = B1; A2 = B2; A3 = B3;
      c0 = d0; c1 = d1; c2 = d2; c3 = d3;
      qd = qn;
    }
  }

  if (lane < 16) accCnt[w][lane] = (float)cnt;
  __syncthreads();

  float* dst = scratch + (size_t)blockIdx.x * SCR_STRIDE;
  for (int i = tid; i < NCAT * DIM; i += 256)
    dst[i] = acc[0][i] + acc[1][i] + acc[2][i] + acc[3][i];
  if (tid < 16)
    dst[2560 + tid] = accCnt[0][tid] + accCnt[1][tid]
                    + accCnt[2][tid] + accCnt[3][tid];
}

// ---------------- K2 fused: slab reduce; last block does EMA ----------------
__global__ __launch_bounds__(256) void k2_fused(
    const float* __restrict__ protos, const float* __restrict__ scratch,
    float* __restrict__ part, float* __restrict__ pused,
    unsigned* __restrict__ ctr) {
  __shared__ float red[4];
  __shared__ int lastFlag;
  const int b = blockIdx.x;          // 0..159
  const int c = b >> 4, p = b & 15;
  const int d = threadIdx.x;
  const int w = d >> 6, lane = d & 63;

  const float* base = scratch + (size_t)p * SPP * SCR_STRIDE + c * DIM + d;
  float s0 = 0.f, s1 = 0.f, s2 = 0.f, s3 = 0.f;
#pragma unroll 4
  for (int s = 0; s < SPP; s += 4) {
    s0 += base[(size_t)s * SCR_STRIDE];
    s1 += base[(size_t)(s + 1) * SCR_STRIDE];
    s2 += base[(size_t)(s + 2) * SCR_STRIDE];
    s3 += base[(size_t)(s + 3) * SCR_STRIDE];
  }
  part[b * 272 + d] = (s0 + s1) + (s2 + s3);

  if (d < 64) {   // 64 lanes <-> 64 slabs: count partial
    float cn = scratch[((size_t)p * SPP + d) * SCR_STRIDE + 2560 + c];
    cn = waveRedSum(cn);
    if (d == 0) part[b * 272 + 256] = cn;
  }

  __threadfence();                   // release this block's part writes
  __syncthreads();
  if (d == 0) lastFlag = (atomicAdd(ctr, 1u) == NCAT * NPART - 1);
  __syncthreads();
  if (!lastFlag) return;
  __threadfence();                   // acquire all blocks' part writes

  // final reduce + EMA for all 10 categories (one block)
  for (int c2 = 0; c2 < NCAT; ++c2) {
    float s = 0.f, cnt = 0.f;
#pragma unroll
    for (int p2 = 0; p2 < NPART; p2++) {
      s += part[(c2 * NPART + p2) * 272 + d];
      cnt += part[(c2 * NPART + p2) * 272 + 256];
    }
    const float pv = protos[c2 * DIM + d];
    const float v = 0.9f * pv + 0.1f * (s / fmaxf(cnt, 1.0f));
    const float vv = waveRedSum(v * v);
    if (lane == 0) red[w] = vv;
    __syncthreads();
    const float n = fmaxf(sqrtf(red[0] + red[1] + red[2] + red[3]), 1e-12f);
    pused[c2 * DIM + d] = (cnt > 0.0f) ? v / n : pv;
    __syncthreads();
  }
}

// ---------------- K3: MFMA sims + loss + aligned output (round-6 proven) ----
__global__ __launch_bounds__(256) void k3_main(
    const float* __restrict__ feats, const int* __restrict__ cats,
    const float* __restrict__ pused, float* __restrict__ out,
    float* __restrict__ partials) {
  __shared__ unsigned short ot[4][16 * 272];   // 34.8 KB
  __shared__ float wloss[4];

  const int tid = threadIdx.x;
  const int w = tid >> 6;
  const int l = tid & 63;
  const int q = l >> 4;
  const int mr = l & 15;
  char* otb = (char*)&ot[w][0];

  // B fragments (prototypes as bf16)
  Frag bfr[8];
  {
    const float* prow = pused + mr * DIM;
#pragma unroll
    for (int s = 0; s < 8; s++) {
      float4 b0 = make_float4(0.f, 0.f, 0.f, 0.f), b1 = b0;
      const int kb = q * 8 + 32 * s;
      if (mr < NCAT) {
        b0 = *(const float4*)(prow + kb);
        b1 = *(const float4*)(prow + kb + 4);
      }
      bfr[s].u[0] = pk2(b0.x, b0.y); bfr[s].u[1] = pk2(b0.z, b0.w);
      bfr[s].u[2] = pk2(b1.x, b1.y); bfr[s].u[3] = pk2(b1.z, b1.w);
    }
  }

  constexpr float KZ = (1.0f / 0.07f) * 1.44269504088896f;
  constexpr float LN2 = 0.69314718056f;
  float lossAcc = 0.0f;

  const int waveG = blockIdx.x * 4 + w;
  const int nwaves = K3_BLOCKS * 4;

  for (int t = waveG; t < B_TOTAL / 16; t += nwaves) {
    const int r0 = t * 16;

    // ---- load F tile, sumsq, bf16 A-frags ----
    const float* frow = feats + (size_t)(r0 + mr) * DIM;
    Frag afr[8];
    float ss = 0.0f;
#pragma unroll
    for (int s = 0; s < 8; s++) {
      const int kb = q * 8 + 32 * s;
      const float4 u0 = *(const float4*)(frow + kb);
      const float4 u1 = *(const float4*)(frow + kb + 4);
      ss += u0.x * u0.x + u0.y * u0.y + u0.z * u0.z + u0.w * u0.w
          + u1.x * u1.x + u1.y * u1.y + u1.z * u1.z + u1.w * u1.w;
      afr[s].u[0] = pk2(u0.x, u0.y); afr[s].u[1] = pk2(u0.z, u0.w);
      afr[s].u[2] = pk2(u1.x, u1.y); afr[s].u[3] = pk2(u1.z, u1.w);
    }
    ss += __shfl_xor(ss, 16, 64);
    ss += __shfl_xor(ss, 32, 64);
    const float inv = __builtin_amdgcn_rsqf(fmaxf(ss, 1e-24f));

    // ---- sims via MFMA ----
    f32x4 acc = {0.f, 0.f, 0.f, 0.f};
#pragma unroll
    for (int s = 0; s < 8; s++)
      acc = __builtin_amdgcn_mfma_f32_16x16x32_bf16(afr[s].v, bfr[s].v, acc, 0, 0, 0);

    // ---- per-reg softmax (row r0+4q+j; lane's category = mr) ----
    float stv[4];
#pragma unroll
    for (int j = 0; j < 4; j++) {
      const float invj = __shfl(inv, 4 * q + j, 64);
      const int catj = cats[r0 + 4 * q + j];
      const float z = acc[j] * (invj * KZ);
      float zm = (mr < NCAT) ? z : -3.0e38f;
#pragma unroll
      for (int m = 1; m < 16; m <<= 1) zm = fmaxf(zm, __shfl_xor(zm, m, 64));
      float e = (mr < NCAT) ? __builtin_amdgcn_exp2f(z - zm) : 0.0f;
      float sv = (mr == catj) ? z : 0.0f;
#pragma unroll
      for (int m = 1; m < 16; m <<= 1) {
        e += __shfl_xor(e, m, 64);
        sv += __shfl_xor(sv, m, 64);
      }
      lossAcc += LN2 * (zm + __builtin_amdgcn_logf(e) - sv);
      stv[j] = sv;
    }

    // ---- aligned vector for row (r0+mr) into swizzled LDS ----
    const int srcg = (mr >> 2) * 16;
    const float s0 = __shfl(stv[0], srcg, 64);
    const float s1 = __shfl(stv[1], srcg, 64);
    const float s2 = __shfl(stv[2], srcg, 64);
    const float s3 = __shfl(stv[3], srcg, 64);
    const int jj = mr & 3;
    const float stm = (jj == 0) ? s0 : ((jj == 1) ? s1 : ((jj == 2) ? s2 : s3));
    const float simn = stm * (0.07f * LN2);
    const float inv2 = __builtin_amdgcn_rsqf(fmaxf(0.58f + 0.42f * simn, 1e-24f));
    const int catm = cats[r0 + mr];
    const float c0f = 0.7f * inv;
    const int psrc = q * 16 + catm;
    const int wrb = mr * 544;
    const int wsz = (mr & 7) << 4;

#pragma unroll
    for (int s = 0; s < 8; s++) {
      const int kb = q * 8 + 32 * s;
      unsigned pw0 = __shfl((int)bfr[s].u[0], psrc, 64);
      unsigned pw1 = __shfl((int)bfr[s].u[1], psrc, 64);
      unsigned pw2 = __shfl((int)bfr[s].u[2], psrc, 64);
      unsigned pw3 = __shfl((int)bfr[s].u[3], psrc, 64);
      const unsigned pws[4] = {pw0, pw1, pw2, pw3};
      float av[8];
#pragma unroll
      for (int h = 0; h < 4; h++) {
        const unsigned fp = afr[s].u[h];
        const unsigned pp = pws[h];
        const float f0 = __uint_as_float(fp << 16);
        const float f1 = __uint_as_float(fp & 0xffff0000u);
        const float p0 = __uint_as_float(pp << 16);
        const float p1 = __uint_as_float(pp & 0xffff0000u);
        av[2 * h]     = (c0f * f0 + 0.3f * p0) * inv2;
        av[2 * h + 1] = (c0f * f1 + 0.3f * p1) * inv2;
      }
      uint4 pk;
      pk.x = pk2(av[0], av[1]); pk.y = pk2(av[2], av[3]);
      pk.z = pk2(av[4], av[5]); pk.w = pk2(av[6], av[7]);
      *(uint4*)(otb + ((wrb + 2 * kb) ^ wsz)) = pk;
    }

    // ---- readback + 16B-aligned non-temporal stores (round-6 form) ----
    float* outr = out + (size_t)r0 * DIM;   // region element e -> outr[1+e]
#pragma unroll
    for (int i = 0; i < 16; ++i) {
      if (i == 15 && l == 63) continue;     // k=1024 handled by edge lane
      const int kidx = i * 64 + l + 1;
      const int rb = 544 * i;
      const int sz = (i & 7) << 4;
      const int cb = 8 * l + 6;             // 2*(4l+3)
      float v[4];
#pragma unroll
      for (int c = 0; c < 4; ++c) {
        int a = (rb + cb + 2 * c) ^ sz;
        if (c > 0 && l == 63)
          a = (544 * (i + 1) + 2 * (c - 1)) ^ (((i + 1) & 7) << 4);
        v[c] = __uint_as_float((unsigned)(*(const unsigned short*)(otb + a)) << 16);
      }
      f32x4 sv = {v[0], v[1], v[2], v[3]};
      __builtin_nontemporal_store(sv, (f32x4*)(outr + 4 * kidx));
    }
    // edge elements: region e = 0,1,2 and e = 4095
    if (l < 3) {
      const float ev = __uint_as_float(
          (unsigned)(*(const unsigned short*)(otb + 2 * l)) << 16);
      __builtin_nontemporal_store(ev, outr + 1 + l);
    }
    if (l == 3) {
      const float ev = __uint_as_float(
          (unsigned)(*(const unsigned short*)(otb + ((544 * 15 + 510) ^ 112))) << 16);
      __builtin_nontemporal_store(ev, outr + 4096);
    }
  }

  const float s = waveRedSum(lossAcc);
  if (l == 0) wloss[w] = s * 0.0625f;   // each row counted by 16 lanes
  __syncthreads();
  if (tid == 0)
    partials[blockIdx.x] = wloss[0] + wloss[1] + wloss[2] + wloss[3];
}

// ---------------- K4: final loss reduction ----------------
__global__ __launch_bounds__(256) void k4_loss(
    const float* __restrict__ partials, float* __restrict__ out) {
  __shared__ float red[4];
  const int tid = threadIdx.x;
  const int w = tid >> 6;
  const int lane = tid & 63;
  float s = 0.0f;
  for (int i = tid; i < K3_BLOCKS; i += 256) s += partials[i];
  s = waveRedSum(s);
  if (lane == 0) red[w] = s;
  __syncthreads();
  if (tid == 0)
    out[0] = (red[0] + red[1] + red[2] + red[3]) * (1.0f / (float)B_TOTAL);
}

// ============================================================================
extern "C" void kernel_launch(void* const* d_in, const int* in_sizes, int n_in,
                              void* d_out, int out_size, void* d_ws, size_t ws_size,
                              hipStream_t stream) {
  const float* feats = (const float*)d_in[0];
  const int* cats = (const int*)d_in[1];
  const float* protos = (const float*)d_in[2];
  float* out = (float*)d_out;
  float* ws = (float*)d_ws;
  unsigned* ctrs = (unsigned*)(ws + WS_CTR);

  k1_segsum<<<K1_BLOCKS, 256, 0, stream>>>(feats, cats, ws + WS_SCRATCH, ctrs);
  k2_fused<<<NCAT * NPART, 256, 0, stream>>>(protos, ws + WS_SCRATCH,
                                             ws + WS_PART, ws + WS_PUSED,
                                             ctrs);
  k3_main<<<K3_BLOCKS, 256, 0, stream>>>(feats, cats, ws + WS_PUSED, out,
                                         ws + WS_LOSSP);
  k4_loss<<<1, 256, 0, stream>>>(ws + WS_LOSSP, out);
}

// Round 12
// 93.742 us; speedup vs baseline: 1.6088x; 1.1586x over previous
//
#include <hip/hip_runtime.h>

#define B_TOTAL 131072
#define DIM 256
#define NCAT 10

#define K1_BLOCKS 1024
#define K1_WAVES  (K1_BLOCKS * 4)            // 4096 waves, 8 quads each
#define K3_BLOCKS 1024
#define NPART 16
#define SLABS_PER_PART (K1_BLOCKS / NPART)   // 64

// ws layout (floats)
#define SCR_STRIDE 2576                       // 2560 sums + 16 counts per block
#define WS_SCRATCH 0
#define WS_PART2   (K1_BLOCKS * SCR_STRIDE)               // [160][272]
#define WS_PUSED   (WS_PART2 + NCAT * NPART * 272)
#define WS_K3PART  (WS_PUSED + NCAT * DIM)

typedef __attribute__((ext_vector_type(8))) short bf16x8;
typedef __attribute__((ext_vector_type(4))) float f32x4;

union Frag { bf16x8 v; unsigned u[4]; };

__device__ __forceinline__ float waveRedSum(float v) {
#pragma unroll
  for (int m = 1; m < 64; m <<= 1) v += __shfl_xor(v, m, 64);
  return v;
}

// pack two fp32 -> packed bf16 pair (RNE, finite inputs)
__device__ __forceinline__ unsigned pk2(float a, float b) {
  unsigned ua = __float_as_uint(a), ub = __float_as_uint(b);
  ua = (ua + 0x7fffu + ((ua >> 16) & 1u)) >> 16;
  ub = (ub + 0x7fffu + ((ub >> 16) & 1u)) >> 16;
  return ua | (ub << 16);
}

// wave-uniform category accumulate: cat is identical across the wave, so this
// is a scalar 10-way branch (s_cmp chain), not a divergent/cndmask select.
#define CAT_ADD(CAT, VX, VY, VZ, VW)                                        \
  {                                                                         \
    const int _cu = __builtin_amdgcn_readfirstlane(CAT);                    \
    if (_cu == 0)      { q0.x += (VX); q0.y += (VY); q0.z += (VZ); q0.w += (VW); } \
    else if (_cu == 1) { q1.x += (VX); q1.y += (VY); q1.z += (VZ); q1.w += (VW); } \
    else if (_cu == 2) { q2.x += (VX); q2.y += (VY); q2.z += (VZ); q2.w += (VW); } \
    else if (_cu == 3) { q3.x += (VX); q3.y += (VY); q3.z += (VZ); q3.w += (VW); } \
    else if (_cu == 4) { q4.x += (VX); q4.y += (VY); q4.z += (VZ); q4.w += (VW); } \
    else if (_cu == 5) { q5.x += (VX); q5.y += (VY); q5.z += (VZ); q5.w += (VW); } \
    else if (_cu == 6) { q6.x += (VX); q6.y += (VY); q6.z += (VZ); q6.w += (VW); } \
    else if (_cu == 7) { q7.x += (VX); q7.y += (VY); q7.z += (VZ); q7.w += (VW); } \
    else if (_cu == 8) { q8.x += (VX); q8.y += (VY); q8.z += (VZ); q8.w += (VW); } \
    else               { q9.x += (VX); q9.y += (VY); q9.z += (VZ); q9.w += (VW); } \
  }

// ---------------- K1: row-normalize + per-block segment sums ----------------
// Register accumulation (10 float4/lane); LDS used once at the flush.
__global__ __launch_bounds__(256) void k1_segsum(
    const float* __restrict__ feats, const int* __restrict__ cats,
    float* __restrict__ scratch) {
  __shared__ float acc[4][NCAT * DIM];   // 40 KB, written once at flush
  __shared__ float accCnt[4][16];

  const int tid = threadIdx.x;
  const int w = tid >> 6;
  const int lane = tid & 63;

  float4 z4 = make_float4(0.f, 0.f, 0.f, 0.f);
  float4 q0 = z4, q1 = z4, q2 = z4, q3 = z4, q4 = z4;
  float4 q5 = z4, q6 = z4, q7 = z4, q8 = z4, q9 = z4;

  int cnt = 0;                       // lane c (<10) counts rows with cat==c
  int qd = blockIdx.x * 4 + w;       // quad index: rows 4qd..4qd+3

  const float* fp = feats + (size_t)qd * 4 * DIM + lane * 4;
  float4 A0 = *(const float4*)(fp);
  float4 A1 = *(const float4*)(fp + DIM);
  float4 A2 = *(const float4*)(fp + 2 * DIM);
  float4 A3 = *(const float4*)(fp + 3 * DIM);
  int c0 = cats[4 * qd], c1 = cats[4 * qd + 1];
  int c2 = cats[4 * qd + 2], c3 = cats[4 * qd + 3];

  for (int it = 0; it < 8; ++it) {
    const int qn = qd + K1_WAVES;
    float4 B0, B1, B2, B3;
    int d0 = 0, d1 = 0, d2 = 0, d3 = 0;
    if (it < 7) {                    // prefetch next quad
      const float* fn = feats + (size_t)qn * 4 * DIM + lane * 4;
      B0 = *(const float4*)(fn);
      B1 = *(const float4*)(fn + DIM);
      B2 = *(const float4*)(fn + 2 * DIM);
      B3 = *(const float4*)(fn + 3 * DIM);
      d0 = cats[4 * qn]; d1 = cats[4 * qn + 1];
      d2 = cats[4 * qn + 2]; d3 = cats[4 * qn + 3];
    }

    float s0 = A0.x * A0.x + A0.y * A0.y + A0.z * A0.z + A0.w * A0.w;
    float s1 = A1.x * A1.x + A1.y * A1.y + A1.z * A1.z + A1.w * A1.w;
    float s2 = A2.x * A2.x + A2.y * A2.y + A2.z * A2.z + A2.w * A2.w;
    float s3 = A3.x * A3.x + A3.y * A3.y + A3.z * A3.z + A3.w * A3.w;
#pragma unroll
    for (int m = 1; m < 64; m <<= 1) {
      s0 += __shfl_xor(s0, m, 64);
      s1 += __shfl_xor(s1, m, 64);
      s2 += __shfl_xor(s2, m, 64);
      s3 += __shfl_xor(s3, m, 64);
    }
    const float i0 = __builtin_amdgcn_rsqf(fmaxf(s0, 1e-24f));
    const float i1 = __builtin_amdgcn_rsqf(fmaxf(s1, 1e-24f));
    const float i2 = __builtin_amdgcn_rsqf(fmaxf(s2, 1e-24f));
    const float i3 = __builtin_amdgcn_rsqf(fmaxf(s3, 1e-24f));

    CAT_ADD(c0, A0.x * i0, A0.y * i0, A0.z * i0, A0.w * i0);
    CAT_ADD(c1, A1.x * i1, A1.y * i1, A1.z * i1, A1.w * i1);
    CAT_ADD(c2, A2.x * i2, A2.y * i2, A2.z * i2, A2.w * i2);
    CAT_ADD(c3, A3.x * i3, A3.y * i3, A3.z * i3, A3.w * i3);

    cnt += (lane == c0) + (lane == c1) + (lane == c2) + (lane == c3);

    if (it < 7) {
      A0 = B0; A1 = B1; A2 = B2; A3 = B3;
      c0 = d0; c1 = d1; c2 = d2; c3 = d3;
      qd = qn;
    }
  }

  // flush: per-wave register sums -> LDS (covers all of acc[w], no init needed)
  if (lane < 16) accCnt[w][lane] = (float)cnt;
  float* aw = acc[w];
  *(float4*)&aw[0 * DIM + lane * 4] = q0;
  *(float4*)&aw[1 * DIM + lane * 4] = q1;
  *(float4*)&aw[2 * DIM + lane * 4] = q2;
  *(float4*)&aw[3 * DIM + lane * 4] = q3;
  *(float4*)&aw[4 * DIM + lane * 4] = q4;
  *(float4*)&aw[5 * DIM + lane * 4] = q5;
  *(float4*)&aw[6 * DIM + lane * 4] = q6;
  *(float4*)&aw[7 * DIM + lane * 4] = q7;
  *(float4*)&aw[8 * DIM + lane * 4] = q8;
  *(float4*)&aw[9 * DIM + lane * 4] = q9;
  __syncthreads();

  float* dst = scratch + (size_t)blockIdx.x * SCR_STRIDE;
  for (int i = tid; i < NCAT * DIM; i += 256)
    dst[i] = acc[0][i] + acc[1][i] + acc[2][i] + acc[3][i];
  if (tid < 16)
    dst[2560 + tid] = accCnt[0][tid] + accCnt[1][tid]
                    + accCnt[2][tid] + accCnt[3][tid];
}

// ---------------- K2a: partial slab reduction (160 blocks) ------------------
__global__ __launch_bounds__(256) void k2a_reduce(
    const float* __restrict__ scratch, float* __restrict__ part) {
  const int b = blockIdx.x;          // 0..159
  const int c = b >> 4, p = b & 15;
  const int d = threadIdx.x;

  const float* base = scratch + (size_t)p * SLABS_PER_PART * SCR_STRIDE + c * DIM + d;
  float s0 = 0.f, s1 = 0.f, s2 = 0.f, s3 = 0.f;
#pragma unroll 4
  for (int s = 0; s < SLABS_PER_PART; s += 4) {
    s0 += base[(size_t)s * SCR_STRIDE];
    s1 += base[(size_t)(s + 1) * SCR_STRIDE];
    s2 += base[(size_t)(s + 2) * SCR_STRIDE];
    s3 += base[(size_t)(s + 3) * SCR_STRIDE];
  }
  part[b * 272 + d] = (s0 + s1) + (s2 + s3);

  if (d < 64) {   // 64 lanes <-> 64 slabs: count partial
    float cn = scratch[((size_t)p * SLABS_PER_PART + d) * SCR_STRIDE + 2560 + c];
    cn = waveRedSum(cn);
    if (d == 0) part[b * 272 + 256] = cn;
  }
}

// ---------------- K2b: final reduce + prototype EMA -> p_used ---------------
__global__ __launch_bounds__(256) void k2b_ema(
    const float* __restrict__ protos, const float* __restrict__ part,
    float* __restrict__ pused) {
  __shared__ float red[4];
  const int c = blockIdx.x;      // 0..9
  const int d = threadIdx.x;     // 0..255
  const int w = d >> 6, lane = d & 63;

  float s = 0.f, cnt = 0.f;
#pragma unroll
  for (int p = 0; p < NPART; p++) {
    s += part[(c * NPART + p) * 272 + d];
    cnt += part[(c * NPART + p) * 272 + 256];
  }

  const float pv = protos[c * DIM + d];
  const float v = 0.9f * pv + 0.1f * (s / fmaxf(cnt, 1.0f));

  float vv = waveRedSum(v * v);
  if (lane == 0) red[w] = vv;
  __syncthreads();
  const float n = fmaxf(sqrtf(red[0] + red[1] + red[2] + red[3]), 1e-12f);

  pused[c * DIM + d] = (cnt > 0.0f) ? v / n : pv;
}

// ---------------- K3: MFMA sims + loss + aligned output (round-6 proven) ----
__global__ __launch_bounds__(256) void k3_main(
    const float* __restrict__ feats, const int* __restrict__ cats,
    const float* __restrict__ pused, float* __restrict__ out,
    float* __restrict__ partials) {
  __shared__ unsigned short ot[4][16 * 272];   // 34.8 KB total
  __shared__ float wloss[4];

  const int tid = threadIdx.x;
  const int w = tid >> 6;
  const int l = tid & 63;
  const int q = l >> 4;
  const int mr = l & 15;
  char* otb = (char*)&ot[w][0];

  // B fragments (prototypes as bf16)
  Frag bfr[8];
  {
    const float* prow = pused + mr * DIM;
#pragma unroll
    for (int s = 0; s < 8; s++) {
      float4 b0 = make_float4(0.f, 0.f, 0.f, 0.f), b1 = b0;
      const int kb = q * 8 + 32 * s;
      if (mr < NCAT) {
        b0 = *(const float4*)(prow + kb);
        b1 = *(const float4*)(prow + kb + 4);
      }
      bfr[s].u[0] = pk2(b0.x, b0.y); bfr[s].u[1] = pk2(b0.z, b0.w);
      bfr[s].u[2] = pk2(b1.x, b1.y); bfr[s].u[3] = pk2(b1.z, b1.w);
    }
  }

  constexpr float KZ = (1.0f / 0.07f) * 1.44269504088896f;
  constexpr float LN2 = 0.69314718056f;
  float lossAcc = 0.0f;

  const int waveG = blockIdx.x * 4 + w;
  const int nwaves = K3_BLOCKS * 4;

  for (int t = waveG; t < B_TOTAL / 16; t += nwaves) {
    const int r0 = t * 16;

    // ---- load F tile, sumsq, bf16 A-frags ----
    const float* frow = feats + (size_t)(r0 + mr) * DIM;
    Frag afr[8];
    float ss = 0.0f;
#pragma unroll
    for (int s = 0; s < 8; s++) {
      const int kb = q * 8 + 32 * s;
      const float4 u0 = *(const float4*)(frow + kb);
      const float4 u1 = *(const float4*)(frow + kb + 4);
      ss += u0.x * u0.x + u0.y * u0.y + u0.z * u0.z + u0.w * u0.w
          + u1.x * u1.x + u1.y * u1.y + u1.z * u1.z + u1.w * u1.w;
      afr[s].u[0] = pk2(u0.x, u0.y); afr[s].u[1] = pk2(u0.z, u0.w);
      afr[s].u[2] = pk2(u1.x, u1.y); afr[s].u[3] = pk2(u1.z, u1.w);
    }
    ss += __shfl_xor(ss, 16, 64);
    ss += __shfl_xor(ss, 32, 64);
    const float inv = __builtin_amdgcn_rsqf(fmaxf(ss, 1e-24f));

    // ---- sims via MFMA ----
    f32x4 acc = {0.f, 0.f, 0.f, 0.f};
#pragma unroll
    for (int s = 0; s < 8; s++)
      acc = __builtin_amdgcn_mfma_f32_16x16x32_bf16(afr[s].v, bfr[s].v, acc, 0, 0, 0);

    // ---- per-reg softmax (row r0+4q+j; lane's category = mr) ----
    float stv[4];
#pragma unroll
    for (int j = 0; j < 4; j++) {
      const float invj = __shfl(inv, 4 * q + j, 64);
      const int catj = cats[r0 + 4 * q + j];
      const float z = acc[j] * (invj * KZ);
      float zm = (mr < NCAT) ? z : -3.0e38f;
#pragma unroll
      for (int m = 1; m < 16; m <<= 1) zm = fmaxf(zm, __shfl_xor(zm, m, 64));
      float e = (mr < NCAT) ? __builtin_amdgcn_exp2f(z - zm) : 0.0f;
      float sv = (mr == catj) ? z : 0.0f;
#pragma unroll
      for (int m = 1; m < 16; m <<= 1) {
        e += __shfl_xor(e, m, 64);
        sv += __shfl_xor(sv, m, 64);
      }
      lossAcc += LN2 * (zm + __builtin_amdgcn_logf(e) - sv);
      stv[j] = sv;
    }

    // ---- aligned vector for row (r0+mr) into swizzled LDS ----
    const int srcg = (mr >> 2) * 16;
    const float s0 = __shfl(stv[0], srcg, 64);
    const float s1 = __shfl(stv[1], srcg, 64);
    const float s2 = __shfl(stv[2], srcg, 64);
    const float s3 = __shfl(stv[3], srcg, 64);
    const int jj = mr & 3;
    const float stm = (jj == 0) ? s0 : ((jj == 1) ? s1 : ((jj == 2) ? s2 : s3));
    const float simn = stm * (0.07f * LN2);
    const float inv2 = __builtin_amdgcn_rsqf(fmaxf(0.58f + 0.42f * simn, 1e-24f));
    const int catm = cats[r0 + mr];
    const float c0f = 0.7f * inv;
    const int psrc = q * 16 + catm;
    const int wrb = mr * 544;           // row byte base
    const int wsz = (mr & 7) << 4;      // 16B-slot XOR swizzle

#pragma unroll
    for (int s = 0; s < 8; s++) {
      const int kb = q * 8 + 32 * s;
      unsigned pw0 = __shfl((int)bfr[s].u[0], psrc, 64);
      unsigned pw1 = __shfl((int)bfr[s].u[1], psrc, 64);
      unsigned pw2 = __shfl((int)bfr[s].u[2], psrc, 64);
      unsigned pw3 = __shfl((int)bfr[s].u[3], psrc, 64);
      const unsigned pws[4] = {pw0, pw1, pw2, pw3};
      float av[8];
#pragma unroll
      for (int h = 0; h < 4; h++) {
        const unsigned fp = afr[s].u[h];
        const unsigned pp = pws[h];
        const float f0 = __uint_as_float(fp << 16);
        const float f1 = __uint_as_float(fp & 0xffff0000u);
        const float p0 = __uint_as_float(pp << 16);
        const float p1 = __uint_as_float(pp & 0xffff0000u);
        av[2 * h]     = (c0f * f0 + 0.3f * p0) * inv2;
        av[2 * h + 1] = (c0f * f1 + 0.3f * p1) * inv2;
      }
      uint4 pk;
      pk.x = pk2(av[0], av[1]); pk.y = pk2(av[2], av[3]);
      pk.z = pk2(av[4], av[5]); pk.w = pk2(av[6], av[7]);
      *(uint4*)(otb + ((wrb + 2 * kb) ^ wsz)) = pk;
    }

    // ---- readback + 16B-aligned non-temporal stores ----
    float* outr = out + (size_t)r0 * DIM;   // region element e -> outr[1+e]
#pragma unroll
    for (int i = 0; i < 16; ++i) {
      if (i == 15 && l == 63) continue;     // k=1024 handled by edge lane
      const int kidx = i * 64 + l + 1;
      const int rb = 544 * i;
      const int sz = (i & 7) << 4;
      const int cb = 8 * l + 6;             // 2*(4l+3)
      float v[4];
#pragma unroll
      for (int c = 0; c < 4; ++c) {
        int a = (rb + cb + 2 * c) ^ sz;
        if (c > 0 && l == 63)
          a = (544 * (i + 1) + 2 * (c - 1)) ^ (((i + 1) & 7) << 4);
        v[c] = __uint_as_float((unsigned)(*(const unsigned short*)(otb + a)) << 16);
      }
      f32x4 sv = {v[0], v[1], v[2], v[3]};
      __builtin_nontemporal_store(sv, (f32x4*)(outr + 4 * kidx));
    }
    // edge elements: region e = 0,1,2 and e = 4095
    if (l < 3) {
      const float ev = __uint_as_float(
          (unsigned)(*(const unsigned short*)(otb + 2 * l)) << 16);
      __builtin_nontemporal_store(ev, outr + 1 + l);
    }
    if (l == 3) {
      const float ev = __uint_as_float(
          (unsigned)(*(const unsigned short*)(otb + ((544 * 15 + 510) ^ 112))) << 16);
      __builtin_nontemporal_store(ev, outr + 4096);
    }
  }

  const float s = waveRedSum(lossAcc);
  if (l == 0) wloss[w] = s * 0.0625f;   // each row counted by 16 lanes
  __syncthreads();
  if (tid == 0)
    partials[blockIdx.x] = wloss[0] + wloss[1] + wloss[2] + wloss[3];
}

// ---------------- K4: final loss reduction ----------------
__global__ __launch_bounds__(256) void k4_loss(
    const float* __restrict__ partials, float* __restrict__ out) {
  __shared__ float red[4];
  const int tid = threadIdx.x;
  const int w = tid >> 6;
  const int lane = tid & 63;
  float s = 0.0f;
  for (int i = tid; i < K3_BLOCKS; i += 256) s += partials[i];
  s = waveRedSum(s);
  if (lane == 0) red[w] = s;
  __syncthreads();
  if (tid == 0)
    out[0] = (red[0] + red[1] + red[2] + red[3]) * (1.0f / (float)B_TOTAL);
}

// ============================================================================
extern "C" void kernel_launch(void* const* d_in, const int* in_sizes, int n_in,
                              void* d_out, int out_size, void* d_ws, size_t ws_size,
                              hipStream_t stream) {
  const float* feats = (const float*)d_in[0];
  const int* cats = (const int*)d_in[1];
  const float* protos = (const float*)d_in[2];
  float* out = (float*)d_out;
  float* ws = (float*)d_ws;

  k1_segsum<<<K1_BLOCKS, 256, 0, stream>>>(feats, cats, ws + WS_SCRATCH);
  k2a_reduce<<<NCAT * NPART, 256, 0, stream>>>(ws + WS_SCRATCH, ws + WS_PART2);
  k2b_ema<<<NCAT, 256, 0, stream>>>(protos, ws + WS_PART2, ws + WS_PUSED);
  k3_main<<<K3_BLOCKS, 256, 0, stream>>>(feats, cats, ws + WS_PUSED, out,
                                         ws + WS_K3PART);
  k4_loss<<<1, 256, 0, stream>>>(ws + WS_K3PART, out);
}

// Round 13
// 88.898 us; speedup vs baseline: 1.6965x; 1.0545x over previous
//
#include <hip/hip_runtime.h>

#define B_TOTAL 131072
#define DIM 256
#define NCAT 10

#define K1_BLOCKS 1024
#define K1_WAVES  (K1_BLOCKS * 4)            // 4096 waves, 8 quads each
#define K3_BLOCKS 1024
#define NPART 16
#define SLABS_PER_PART (K1_BLOCKS / NPART)   // 64

// ws layout (floats)
#define SCR_STRIDE 2576                       // 2560 sums + 16 counts per block
#define WS_SCRATCH 0
#define WS_PART2   (K1_BLOCKS * SCR_STRIDE)               // [160][272]
#define WS_PUSED   (WS_PART2 + NCAT * NPART * 272)
#define WS_K3PART  (WS_PUSED + NCAT * DIM)

typedef __attribute__((ext_vector_type(8))) short bf16x8;
typedef __attribute__((ext_vector_type(4))) float f32x4;

union Frag { bf16x8 v; unsigned u[4]; };

__device__ __forceinline__ float waveRedSum(float v) {
#pragma unroll
  for (int m = 1; m < 64; m <<= 1) v += __shfl_xor(v, m, 64);
  return v;
}

// pack two fp32 -> packed bf16 pair (RNE, finite inputs)
__device__ __forceinline__ unsigned pk2(float a, float b) {
  unsigned ua = __float_as_uint(a), ub = __float_as_uint(b);
  ua = (ua + 0x7fffu + ((ua >> 16) & 1u)) >> 16;
  ub = (ub + 0x7fffu + ((ub >> 16) & 1u)) >> 16;
  return ua | (ub << 16);
}

// ---------------- K1: row-normalize + per-block segment sums (no atomics) ----
__global__ __launch_bounds__(256) void k1_segsum(
    const float* __restrict__ feats, const int* __restrict__ cats,
    float* __restrict__ scratch) {
  __shared__ float acc[4][NCAT * DIM];   // 40 KB -> 4 blocks/CU, 16 waves/CU
  __shared__ float accCnt[4][16];

  const int tid = threadIdx.x;
  const int w = tid >> 6;
  const int lane = tid & 63;

  for (int i = tid; i < 4 * NCAT * DIM; i += 256) (&acc[0][0])[i] = 0.0f;
  __syncthreads();

  float* accW = acc[w];
  int cnt = 0;                       // lane c (<10) counts rows with cat==c
  int qd = blockIdx.x * 4 + w;       // quad index: rows 4qd..4qd+3

  const float* fp = feats + (size_t)qd * 4 * DIM + lane * 4;
  float4 A0 = *(const float4*)(fp);
  float4 A1 = *(const float4*)(fp + DIM);
  float4 A2 = *(const float4*)(fp + 2 * DIM);
  float4 A3 = *(const float4*)(fp + 3 * DIM);
  int c0 = cats[4 * qd], c1 = cats[4 * qd + 1];
  int c2 = cats[4 * qd + 2], c3 = cats[4 * qd + 3];

  for (int it = 0; it < 8; ++it) {
    const int qn = qd + K1_WAVES;
    float4 B0, B1, B2, B3;
    int d0 = 0, d1 = 0, d2 = 0, d3 = 0;
    if (it < 7) {                    // prefetch next quad
      const float* fn = feats + (size_t)qn * 4 * DIM + lane * 4;
      B0 = *(const float4*)(fn);
      B1 = *(const float4*)(fn + DIM);
      B2 = *(const float4*)(fn + 2 * DIM);
      B3 = *(const float4*)(fn + 3 * DIM);
      d0 = cats[4 * qn]; d1 = cats[4 * qn + 1];
      d2 = cats[4 * qn + 2]; d3 = cats[4 * qn + 3];
    }

    float s0 = A0.x * A0.x + A0.y * A0.y + A0.z * A0.z + A0.w * A0.w;
    float s1 = A1.x * A1.x + A1.y * A1.y + A1.z * A1.z + A1.w * A1.w;
    float s2 = A2.x * A2.x + A2.y * A2.y + A2.z * A2.z + A2.w * A2.w;
    float s3 = A3.x * A3.x + A3.y * A3.y + A3.z * A3.z + A3.w * A3.w;
#pragma unroll
    for (int m = 1; m < 64; m <<= 1) {
      s0 += __shfl_xor(s0, m, 64);
      s1 += __shfl_xor(s1, m, 64);
      s2 += __shfl_xor(s2, m, 64);
      s3 += __shfl_xor(s3, m, 64);
    }
    const float i0 = __builtin_amdgcn_rsqf(fmaxf(s0, 1e-24f));
    const float i1 = __builtin_amdgcn_rsqf(fmaxf(s1, 1e-24f));
    const float i2 = __builtin_amdgcn_rsqf(fmaxf(s2, 1e-24f));
    const float i3 = __builtin_amdgcn_rsqf(fmaxf(s3, 1e-24f));

    float4* p;
    float4 t;
    p = (float4*)&accW[c0 * DIM + lane * 4]; t = *p;
    t.x += A0.x * i0; t.y += A0.y * i0; t.z += A0.z * i0; t.w += A0.w * i0; *p = t;
    p = (float4*)&accW[c1 * DIM + lane * 4]; t = *p;
    t.x += A1.x * i1; t.y += A1.y * i1; t.z += A1.z * i1; t.w += A1.w * i1; *p = t;
    p = (float4*)&accW[c2 * DIM + lane * 4]; t = *p;
    t.x += A2.x * i2; t.y += A2.y * i2; t.z += A2.z * i2; t.w += A2.w * i2; *p = t;
    p = (float4*)&accW[c3 * DIM + lane * 4]; t = *p;
    t.x += A3.x * i3; t.y += A3.y * i3; t.z += A3.z * i3; t.w += A3.w * i3; *p = t;

    cnt += (lane == c0) + (lane == c1) + (lane == c2) + (lane == c3);

    if (it < 7) {
      A0 = B0; A1 = B1; A2 = B2; A3 = B3;
      c0 = d0; c1 = d1; c2 = d2; c3 = d3;
      qd = qn;
    }
  }

  if (lane < 16) accCnt[w][lane] = (float)cnt;
  __syncthreads();

  float* dst = scratch + (size_t)blockIdx.x * SCR_STRIDE;
  for (int i = tid; i < NCAT * DIM; i += 256)
    dst[i] = acc[0][i] + acc[1][i] + acc[2][i] + acc[3][i];
  if (tid < 16)
    dst[2560 + tid] = accCnt[0][tid] + accCnt[1][tid]
                    + accCnt[2][tid] + accCnt[3][tid];
}

// ---------------- K2a: partial slab reduction (160 blocks) ------------------
__global__ __launch_bounds__(256) void k2a_reduce(
    const float* __restrict__ scratch, float* __restrict__ part) {
  const int b = blockIdx.x;          // 0..159
  const int c = b >> 4, p = b & 15;
  const int d = threadIdx.x;

  const float* base = scratch + (size_t)p * SLABS_PER_PART * SCR_STRIDE + c * DIM + d;
  float s0 = 0.f, s1 = 0.f, s2 = 0.f, s3 = 0.f;
#pragma unroll 4
  for (int s = 0; s < SLABS_PER_PART; s += 4) {
    s0 += base[(size_t)s * SCR_STRIDE];
    s1 += base[(size_t)(s + 1) * SCR_STRIDE];
    s2 += base[(size_t)(s + 2) * SCR_STRIDE];
    s3 += base[(size_t)(s + 3) * SCR_STRIDE];
  }
  part[b * 272 + d] = (s0 + s1) + (s2 + s3);

  if (d < 64) {   // 64 lanes <-> 64 slabs: count partial
    float cn = scratch[((size_t)p * SLABS_PER_PART + d) * SCR_STRIDE + 2560 + c];
    cn = waveRedSum(cn);
    if (d == 0) part[b * 272 + 256] = cn;
  }
}

// ---------------- K2b: final reduce + prototype EMA -> p_used ---------------
__global__ __launch_bounds__(256) void k2b_ema(
    const float* __restrict__ protos, const float* __restrict__ part,
    float* __restrict__ pused) {
  __shared__ float red[4];
  const int c = blockIdx.x;      // 0..9
  const int d = threadIdx.x;     // 0..255
  const int w = d >> 6, lane = d & 63;

  float s = 0.f, cnt = 0.f;
#pragma unroll
  for (int p = 0; p < NPART; p++) {
    s += part[(c * NPART + p) * 272 + d];
    cnt += part[(c * NPART + p) * 272 + 256];
  }

  const float pv = protos[c * DIM + d];
  const float v = 0.9f * pv + 0.1f * (s / fmaxf(cnt, 1.0f));

  float vv = waveRedSum(v * v);
  if (lane == 0) red[w] = vv;
  __syncthreads();
  const float n = fmaxf(sqrtf(red[0] + red[1] + red[2] + red[3]), 1e-12f);

  pused[c * DIM + d] = (cnt > 0.0f) ? v / n : pv;
}

// ---------------- K3: MFMA sims + loss + aligned output --------------------
// Wave handles 16-row tiles. A-frag: lane l -> row (l&15), k=(l>>4)*8+j+32s.
// B-frag: lane l -> cat (l&15). D: col=lane&15, row=(lane>>4)*4+reg.
// Output: bf16 LDS tile (row stride 272 ushorts, XOR-swizzled 16B slots),
// read back element-exact, stored as 16B-aligned NON-TEMPORAL dwordx4
// (keeps features resident in L3; the +1 offset handled by edge dwords).
__global__ __launch_bounds__(256) void k3_main(
    const float* __restrict__ feats, const int* __restrict__ cats,
    const float* __restrict__ pused, float* __restrict__ out,
    float* __restrict__ partials) {
  __shared__ unsigned short ot[4][16 * 272];   // 34.8 KB total
  __shared__ float wloss[4];

  const int tid = threadIdx.x;
  const int w = tid >> 6;
  const int l = tid & 63;
  const int q = l >> 4;
  const int mr = l & 15;
  char* otb = (char*)&ot[w][0];

  // B fragments (prototypes as bf16)
  Frag bfr[8];
  {
    const float* prow = pused + mr * DIM;
#pragma unroll
    for (int s = 0; s < 8; s++) {
      float4 b0 = make_float4(0.f, 0.f, 0.f, 0.f), b1 = b0;
      const int kb = q * 8 + 32 * s;
      if (mr < NCAT) {
        b0 = *(const float4*)(prow + kb);
        b1 = *(const float4*)(prow + kb + 4);
      }
      bfr[s].u[0] = pk2(b0.x, b0.y); bfr[s].u[1] = pk2(b0.z, b0.w);
      bfr[s].u[2] = pk2(b1.x, b1.y); bfr[s].u[3] = pk2(b1.z, b1.w);
    }
  }

  constexpr float KZ = (1.0f / 0.07f) * 1.44269504088896f;
  constexpr float LN2 = 0.69314718056f;
  float lossAcc = 0.0f;

  const int waveG = blockIdx.x * 4 + w;
  const int nwaves = K3_BLOCKS * 4;

  for (int t = waveG; t < B_TOTAL / 16; t += nwaves) {
    const int r0 = t * 16;

    // ---- load F tile, sumsq, bf16 A-frags ----
    const float* frow = feats + (size_t)(r0 + mr) * DIM;
    Frag afr[8];
    float ss = 0.0f;
#pragma unroll
    for (int s = 0; s < 8; s++) {
      const int kb = q * 8 + 32 * s;
      const float4 u0 = *(const float4*)(frow + kb);
      const float4 u1 = *(const float4*)(frow + kb + 4);
      ss += u0.x * u0.x + u0.y * u0.y + u0.z * u0.z + u0.w * u0.w
          + u1.x * u1.x + u1.y * u1.y + u1.z * u1.z + u1.w * u1.w;
      afr[s].u[0] = pk2(u0.x, u0.y); afr[s].u[1] = pk2(u0.z, u0.w);
      afr[s].u[2] = pk2(u1.x, u1.y); afr[s].u[3] = pk2(u1.z, u1.w);
    }
    ss += __shfl_xor(ss, 16, 64);
    ss += __shfl_xor(ss, 32, 64);
    const float inv = __builtin_amdgcn_rsqf(fmaxf(ss, 1e-24f));

    // ---- sims via MFMA ----
    f32x4 acc = {0.f, 0.f, 0.f, 0.f};
#pragma unroll
    for (int s = 0; s < 8; s++)
      acc = __builtin_amdgcn_mfma_f32_16x16x32_bf16(afr[s].v, bfr[s].v, acc, 0, 0, 0);

    // ---- per-reg softmax (row r0+4q+j; lane's category = mr) ----
    float stv[4];
#pragma unroll
    for (int j = 0; j < 4; j++) {
      const float invj = __shfl(inv, 4 * q + j, 64);
      const int catj = cats[r0 + 4 * q + j];
      const float z = acc[j] * (invj * KZ);
      float zm = (mr < NCAT) ? z : -3.0e38f;
#pragma unroll
      for (int m = 1; m < 16; m <<= 1) zm = fmaxf(zm, __shfl_xor(zm, m, 64));
      float e = (mr < NCAT) ? __builtin_amdgcn_exp2f(z - zm) : 0.0f;
      float sv = (mr == catj) ? z : 0.0f;
#pragma unroll
      for (int m = 1; m < 16; m <<= 1) {
        e += __shfl_xor(e, m, 64);
        sv += __shfl_xor(sv, m, 64);
      }
      lossAcc += LN2 * (zm + __builtin_amdgcn_logf(e) - sv);
      stv[j] = sv;
    }

    // ---- aligned vector for row (r0+mr) into swizzled LDS ----
    const int srcg = (mr >> 2) * 16;
    const float s0 = __shfl(stv[0], srcg, 64);
    const float s1 = __shfl(stv[1], srcg, 64);
    const float s2 = __shfl(stv[2], srcg, 64);
    const float s3 = __shfl(stv[3], srcg, 64);
    const int jj = mr & 3;
    const float stm = (jj == 0) ? s0 : ((jj == 1) ? s1 : ((jj == 2) ? s2 : s3));
    const float simn = stm * (0.07f * LN2);
    const float inv2 = __builtin_amdgcn_rsqf(fmaxf(0.58f + 0.42f * simn, 1e-24f));
    const int catm = cats[r0 + mr];
    const float c0f = 0.7f * inv;
    const int psrc = q * 16 + catm;
    const int wrb = mr * 544;           // row byte base
    const int wsz = (mr & 7) << 4;      // 16B-slot XOR swizzle

#pragma unroll
    for (int s = 0; s < 8; s++) {
      const int kb = q * 8 + 32 * s;
      unsigned pw0 = __shfl((int)bfr[s].u[0], psrc, 64);
      unsigned pw1 = __shfl((int)bfr[s].u[1], psrc, 64);
      unsigned pw2 = __shfl((int)bfr[s].u[2], psrc, 64);
      unsigned pw3 = __shfl((int)bfr[s].u[3], psrc, 64);
      const unsigned pws[4] = {pw0, pw1, pw2, pw3};
      float av[8];
#pragma unroll
      for (int h = 0; h < 4; h++) {
        const unsigned fp = afr[s].u[h];
        const unsigned pp = pws[h];
        const float f0 = __uint_as_float(fp << 16);
        const float f1 = __uint_as_float(fp & 0xffff0000u);
        const float p0 = __uint_as_float(pp << 16);
        const float p1 = __uint_as_float(pp & 0xffff0000u);
        av[2 * h]     = (c0f * f0 + 0.3f * p0) * inv2;
        av[2 * h + 1] = (c0f * f1 + 0.3f * p1) * inv2;
      }
      uint4 pk;
      pk.x = pk2(av[0], av[1]); pk.y = pk2(av[2], av[3]);
      pk.z = pk2(av[4], av[5]); pk.w = pk2(av[6], av[7]);
      *(uint4*)(otb + ((wrb + 2 * kb) ^ wsz)) = pk;
    }

    // ---- readback + 16B-aligned non-temporal stores ----
    float* outr = out + (size_t)r0 * DIM;   // region element e -> outr[1+e]
#pragma unroll
    for (int i = 0; i < 16; ++i) {
      if (i == 15 && l == 63) continue;     // k=1024 handled by edge lane
      const int kidx = i * 64 + l + 1;
      const int rb = 544 * i;
      const int sz = (i & 7) << 4;
      const int cb = 8 * l + 6;             // 2*(4l+3)
      float v[4];
#pragma unroll
      for (int c = 0; c < 4; ++c) {
        int a = (rb + cb + 2 * c) ^ sz;
        if (c > 0 && l == 63)
          a = (544 * (i + 1) + 2 * (c - 1)) ^ (((i + 1) & 7) << 4);
        v[c] = __uint_as_float((unsigned)(*(const unsigned short*)(otb + a)) << 16);
      }
      f32x4 sv = {v[0], v[1], v[2], v[3]};
      __builtin_nontemporal_store(sv, (f32x4*)(outr + 4 * kidx));
    }
    // edge elements: region e = 0,1,2 (row0 cols 0..2) and e = 4095 (row15 col255)
    if (l < 3) {
      const float ev = __uint_as_float(
          (unsigned)(*(const unsigned short*)(otb + 2 * l)) << 16);
      __builtin_nontemporal_store(ev, outr + 1 + l);
    }
    if (l == 3) {
      const float ev = __uint_as_float(
          (unsigned)(*(const unsigned short*)(otb + ((544 * 15 + 510) ^ 112))) << 16);
      __builtin_nontemporal_store(ev, outr + 4096);
    }
  }

  const float s = waveRedSum(lossAcc);
  if (l == 0) wloss[w] = s * 0.0625f;   // each row counted by 16 lanes
  __syncthreads();
  if (tid == 0)
    partials[blockIdx.x] = wloss[0] + wloss[1] + wloss[2] + wloss[3];
}

// ---------------- K4: final loss reduction ----------------
__global__ __launch_bounds__(256) void k4_loss(
    const float* __restrict__ partials, float* __restrict__ out) {
  __shared__ float red[4];
  const int tid = threadIdx.x;
  const int w = tid >> 6;
  const int lane = tid & 63;
  float s = 0.0f;
  for (int i = tid; i < K3_BLOCKS; i += 256) s += partials[i];
  s = waveRedSum(s);
  if (lane == 0) red[w] = s;
  __syncthreads();
  if (tid == 0)
    out[0] = (red[0] + red[1] + red[2] + red[3]) * (1.0f / (float)B_TOTAL);
}

extern "C" void kernel_launch(void* const* d_in, const int* in_sizes, int n_in,
                              void* d_out, int out_size, void* d_ws, size_t ws_size,
                              hipStream_t stream) {
  const float* feats = (const float*)d_in[0];
  const int* cats = (const int*)d_in[1];
  const float* protos = (const float*)d_in[2];
  float* out = (float*)d_out;
  float* ws = (float*)d_ws;

  k1_segsum<<<K1_BLOCKS, 256, 0, stream>>>(feats, cats, ws + WS_SCRATCH);
  k2a_reduce<<<NCAT * NPART, 256, 0, stream>>>(ws + WS_SCRATCH, ws + WS_PART2);
  k2b_ema<<<NCAT, 256, 0, stream>>>(protos, ws + WS_PART2, ws + WS_PUSED);
  k3_main<<<K3_BLOCKS, 256, 0, stream>>>(feats, cats, ws + WS_PUSED, out,
                                         ws + WS_K3PART);
  k4_loss<<<1, 256, 0, stream>>>(ws + WS_K3PART, out);
}